// Round 1
// baseline (804.583 us; speedup 1.0000x reference)
//
#include <hip/hip_runtime.h>

// Problem constants
#define DK     768
#define M_ROWS 2048          // 8 * 256
#define N_ATOM 1001
#define N_BOND 301
#define ATOM_ELEMS 2050048   // 8*256*1001
#define P_ELEMS    616448    // 8*256*301
#define BOND_F4    39452672u // 8*256*256*301 / 4

// ---------------- GEMM: C[m,n] = sum_k A[m,k]*W[n,k] (+ bias[n]) ----------------
// A: M_ROWS x 768 row-major. W: N rows, row stride ldw (use first 768 cols of each row).
#define BM 128
#define BN 64
#define BK 16

__global__ __launch_bounds__(256) void gemm_nt_bias(
    const float* __restrict__ A,
    const float* __restrict__ W,
    const float* __restrict__ bias,   // may be nullptr
    float* __restrict__ C,
    int N, int ldw)
{
    __shared__ float As[BK][BM + 4];
    __shared__ float Bs[BK][BN + 4];

    const int tid = threadIdx.x;
    const int tx  = tid & 15;   // n direction, 4 cols each
    const int ty  = tid >> 4;   // m direction, 8 rows each
    const int m0  = blockIdx.y * BM;
    const int n0  = blockIdx.x * BN;

    float acc[8][4];
    #pragma unroll
    for (int i = 0; i < 8; ++i)
        #pragma unroll
        for (int j = 0; j < 4; ++j) acc[i][j] = 0.f;

    for (int k0 = 0; k0 < DK; k0 += BK) {
        // stage A tile: 128x16 = 2048 elems, 8 per thread (coalesced in k)
        #pragma unroll
        for (int i = 0; i < 8; ++i) {
            int idx = tid + i * 256;
            int k = idx & 15, m = idx >> 4;
            As[k][m] = A[(m0 + m) * DK + k0 + k];
        }
        // stage B tile: 64x16 = 1024 elems, 4 per thread, guard N edge
        #pragma unroll
        for (int i = 0; i < 4; ++i) {
            int idx = tid + i * 256;
            int k = idx & 15, n = idx >> 4;
            float v = 0.f;
            if (n0 + n < N) v = W[(size_t)(n0 + n) * ldw + k0 + k];
            Bs[k][n] = v;
        }
        __syncthreads();

        #pragma unroll
        for (int kk = 0; kk < BK; ++kk) {
            float4 a0 = *(const float4*)&As[kk][ty * 8];
            float4 a1 = *(const float4*)&As[kk][ty * 8 + 4];
            float4 b0 = *(const float4*)&Bs[kk][tx * 4];
            float av[8] = {a0.x, a0.y, a0.z, a0.w, a1.x, a1.y, a1.z, a1.w};
            float bv[4] = {b0.x, b0.y, b0.z, b0.w};
            #pragma unroll
            for (int i = 0; i < 8; ++i)
                #pragma unroll
                for (int j = 0; j < 4; ++j)
                    acc[i][j] += av[i] * bv[j];
        }
        __syncthreads();
    }

    // epilogue
    #pragma unroll
    for (int i = 0; i < 8; ++i) {
        int m = m0 + ty * 8 + i;
        #pragma unroll
        for (int j = 0; j < 4; ++j) {
            int n = n0 + tx * 4 + j;
            if (n < N) {
                float v = acc[i][j];
                if (bias) v += bias[n];
                C[(size_t)m * N + n] = v;
            }
        }
    }
}

// ---------------- bond broadcast: out[b,i,j,n] = p1[b,i,n] + p2b[b,j,n] ----------------
// p2b already contains + bb. Flat float4 grid-stride over the bond region.
__global__ __launch_bounds__(256) void bond_bcast(
    const float* __restrict__ p1,   // (2048, 301), row = b*256+i
    const float* __restrict__ p2b,  // (2048, 301), row = b*256+j
    float4* __restrict__ out)
{
    unsigned idx    = blockIdx.x * blockDim.x + threadIdx.x;
    unsigned stride = gridDim.x * blockDim.x;
    for (unsigned f = idx; f < BOND_F4; f += stride) {
        unsigned e = f * 4u;
        float vv[4];
        #pragma unroll
        for (int c = 0; c < 4; ++c) {
            unsigned ee  = e + (unsigned)c;
            unsigned row = ee / 301u;          // magic-mul, ee < 2^31
            unsigned n   = ee - row * 301u;
            unsigned bi  = row >> 8;           // b*256 + i  (< 2048)
            unsigned b   = row >> 16;          // < 8
            unsigned j   = row & 255u;
            vv[c] = p1[bi * 301u + n] + p2b[(b * 256u + j) * 301u + n];
        }
        float4 v = make_float4(vv[0], vv[1], vv[2], vv[3]);
        out[f] = v;
    }
}

extern "C" void kernel_launch(void* const* d_in, const int* in_sizes, int n_in,
                              void* d_out, int out_size, void* d_ws, size_t ws_size,
                              hipStream_t stream) {
    const float* x  = (const float*)d_in[0];   // (8,256,768)
    const float* Wa = (const float*)d_in[1];   // (1001,768)
    const float* ba = (const float*)d_in[2];   // (1001,)
    const float* Wb = (const float*)d_in[3];   // (301,1536)
    const float* bb = (const float*)d_in[4];   // (301,)

    float* out  = (float*)d_out;
    float* atom = out;                 // 2,050,048 floats
    float* bond = out + ATOM_ELEMS;    // 157,810,688 floats (16B-aligned: 2050048 % 4 == 0)

    float* p1 = (float*)d_ws;          // 616,448 floats
    float* p2 = p1 + P_ELEMS;          // 616,448 floats  (total ~4.93 MB of ws)

    dim3 blk(256);
    // atom logits: N=1001, ldw=768, bias=ba -> d_out
    gemm_nt_bias<<<dim3((N_ATOM + BN - 1) / BN, M_ROWS / BM), blk, 0, stream>>>(
        x, Wa, ba, atom, N_ATOM, DK);
    // p1: W1 = Wb[:, :768], no bias
    gemm_nt_bias<<<dim3((N_BOND + BN - 1) / BN, M_ROWS / BM), blk, 0, stream>>>(
        x, Wb, nullptr, p1, N_BOND, 2 * DK);
    // p2: W2 = Wb[:, 768:], bias=bb folded here
    gemm_nt_bias<<<dim3((N_BOND + BN - 1) / BN, M_ROWS / BM), blk, 0, stream>>>(
        x, Wb + DK, bb, p2, N_BOND, 2 * DK);
    // bond broadcast
    bond_bcast<<<dim3(4096), blk, 0, stream>>>(p1, p2, (float4*)bond);
}

// Round 2
// 352.672 us; speedup vs baseline: 2.2814x; 2.2814x over previous
//
#include <hip/hip_runtime.h>

// ---------------- problem constants ----------------
#define DK      768
#define M_ROWS  2048          // 8*256
#define N_ATOM  1001
#define N_BOND  301
#define N_TOT   1603          // 1001 + 2*301
#define N_PADR  1664          // 26 * 64 (padded rows of Wcat)
#define ATOM_ELEMS 2050048    // 2048*1001
#define P_ELEMS    616448     // 2048*301
#define SLAB       77056      // 256*301

typedef __attribute__((ext_vector_type(4))) float f32x4;
typedef __attribute__((ext_vector_type(8))) short bf16x8;

// exact RNE float->bf16 (no API dependency)
static __device__ __forceinline__ unsigned short f2bf(float f) {
    unsigned u = __float_as_uint(f);
    u += 0x7FFFu + ((u >> 16) & 1u);
    return (unsigned short)(u >> 16);
}

// ---------------- pack: x, Wa, Wb(interleaved W1/W2) -> bf16 ----------------
// wcat row r: r<1001 -> Wa[r]; 1001<=r<1603: q=r-1001, even->W1[q/2], odd->W2[q/2]; else 0
__global__ __launch_bounds__(256) void pack_bf16(
    const float* __restrict__ x, const float* __restrict__ Wa,
    const float* __restrict__ Wb,
    ushort* __restrict__ xb, ushort* __restrict__ wcat)
{
    const int NX4 = (M_ROWS * DK) / 4;   // 393216
    const int NW4 = (N_PADR * DK) / 4;   // 319488
    int t = blockIdx.x * 256 + threadIdx.x;
    if (t < NX4) {
        float4 v = ((const float4*)x)[t];
        ushort4 o;
        o.x = f2bf(v.x); o.y = f2bf(v.y); o.z = f2bf(v.z); o.w = f2bf(v.w);
        ((ushort4*)xb)[t] = o;
    } else if (t < NX4 + NW4) {
        int u = t - NX4;
        int r = u / 192;                 // 192 float4 per row
        int c = (u - r * 192) * 4;
        float4 v = make_float4(0.f, 0.f, 0.f, 0.f);
        if (r < N_ATOM) {
            v = *(const float4*)(Wa + (size_t)r * DK + c);
        } else if (r < N_TOT) {
            int q = r - N_ATOM;
            v = *(const float4*)(Wb + (size_t)(q >> 1) * (2 * DK) + (q & 1) * DK + c);
        }
        ushort4 o;
        o.x = f2bf(v.x); o.y = f2bf(v.y); o.z = f2bf(v.z); o.w = f2bf(v.w);
        ((ushort4*)wcat)[u] = o;
    }
}

// ---------------- fused bf16 MFMA GEMM ----------------
// C[m,n] = sum_k xb[m,k] * wcat[n,k];  epilogue splits n into atom / p1 / p2(+bb)
#define BM 64
#define BN 64
#define BKT 64
#define ROWB 144   // 64 bf16 = 128B + 16B pad -> <=2-way LDS conflicts

__global__ __launch_bounds__(256) void gemm_mfma(
    const ushort* __restrict__ xb, const ushort* __restrict__ wcat,
    const float* __restrict__ ba, const float* __restrict__ bb,
    float* __restrict__ atom, float* __restrict__ p1, float* __restrict__ p2)
{
    __shared__ char As[64 * ROWB];
    __shared__ char Bs[64 * ROWB];

    const int tid  = threadIdx.x;
    const int lane = tid & 63;
    const int wid  = tid >> 6;     // 4 waves: 2x2
    const int wr   = wid >> 1;     // m half
    const int wc   = wid & 1;      // n half
    const int m0   = blockIdx.y * BM;
    const int n0   = blockIdx.x * BN;

    f32x4 acc[2][2] = {};

    // staging slots: tile = 64 rows x 8 chunks(16B). thread does slots tid, tid+256
    const int r0 = tid >> 3,          c0 = tid & 7;
    const int r1 = (tid + 256) >> 3,  c1 = tid & 7;   // (tid+256)&7 == tid&7

    const ushort* Ag = xb   + (size_t)m0 * DK;
    const ushort* Bg = wcat + (size_t)n0 * DK;

    for (int k0 = 0; k0 < DK; k0 += BKT) {
        uint4 a0 = *(const uint4*)(Ag + (size_t)r0 * DK + k0 + c0 * 8);
        uint4 a1 = *(const uint4*)(Ag + (size_t)r1 * DK + k0 + c1 * 8);
        uint4 b0 = *(const uint4*)(Bg + (size_t)r0 * DK + k0 + c0 * 8);
        uint4 b1 = *(const uint4*)(Bg + (size_t)r1 * DK + k0 + c1 * 8);
        __syncthreads();   // previous compute done before overwrite
        *(uint4*)(As + r0 * ROWB + c0 * 16) = a0;
        *(uint4*)(As + r1 * ROWB + c1 * 16) = a1;
        *(uint4*)(Bs + r0 * ROWB + c0 * 16) = b0;
        *(uint4*)(Bs + r1 * ROWB + c1 * 16) = b1;
        __syncthreads();
        #pragma unroll
        for (int ks = 0; ks < 2; ++ks) {
            const int kc = ks * 4 + (lane >> 4);   // 16B chunk index in row
            bf16x8 af[2], bfr[2];
            #pragma unroll
            for (int i = 0; i < 2; ++i) {
                int ra = wr * 32 + i * 16 + (lane & 15);
                af[i]  = *(const bf16x8*)(As + ra * ROWB + kc * 16);
                int rb = wc * 32 + i * 16 + (lane & 15);
                bfr[i] = *(const bf16x8*)(Bs + rb * ROWB + kc * 16);
            }
            #pragma unroll
            for (int i = 0; i < 2; ++i)
                #pragma unroll
                for (int j = 0; j < 2; ++j)
                    acc[i][j] = __builtin_amdgcn_mfma_f32_16x16x32_bf16(
                        af[i], bfr[j], acc[i][j], 0, 0, 0);
        }
    }

    // epilogue: D col = lane&15, row = (lane>>4)*4 + reg  [m89-verified]
    #pragma unroll
    for (int i = 0; i < 2; ++i) {
        #pragma unroll
        for (int j = 0; j < 2; ++j) {
            #pragma unroll
            for (int reg = 0; reg < 4; ++reg) {
                int m = m0 + wr * 32 + i * 16 + (lane >> 4) * 4 + reg;
                int n = n0 + wc * 32 + j * 16 + (lane & 15);
                float v = acc[i][j][reg];
                if (n < N_ATOM) {
                    atom[(size_t)m * N_ATOM + n] = v + ba[n];
                } else if (n < N_TOT) {
                    int q = n - N_ATOM, rr = q >> 1;
                    if (q & 1) p2[(size_t)m * N_BOND + rr] = v + bb[rr];
                    else       p1[(size_t)m * N_BOND + rr] = v;
                }
            }
        }
    }
}

// ---------------- bond broadcast: out[bi, j, n] = p1[bi,n] + p2[b*256+j, n] ----------------
// thread owns fixed n; p1 value lives in a register across the whole j loop.
__global__ __launch_bounds__(320) void bond_bcast(
    const float* __restrict__ p1, const float* __restrict__ p2,
    float* __restrict__ out)
{
    const int bi = blockIdx.x;          // b*256 + i, 0..2047
    const int b  = bi >> 8;
    const int n  = threadIdx.x;         // 0..319
    const bool act = (n < N_BOND);

    float p1v = act ? p1[(size_t)bi * N_BOND + n] : 0.f;
    const float* p2b = p2 + (size_t)(b << 8) * N_BOND;
    float* o = out + (size_t)bi * SLAB;

    for (int j = 0; j < 256; ++j) {
        if (act) {
            float v = p1v + p2b[(size_t)j * N_BOND + n];
            __builtin_nontemporal_store(v, &o[(size_t)j * N_BOND + n]);
        }
    }
}

// ---------------- launch ----------------
extern "C" void kernel_launch(void* const* d_in, const int* in_sizes, int n_in,
                              void* d_out, int out_size, void* d_ws, size_t ws_size,
                              hipStream_t stream) {
    const float* x  = (const float*)d_in[0];   // (8,256,768)
    const float* Wa = (const float*)d_in[1];   // (1001,768)
    const float* ba = (const float*)d_in[2];   // (1001,)
    const float* Wb = (const float*)d_in[3];   // (301,1536)
    const float* bb = (const float*)d_in[4];   // (301,)

    float* out  = (float*)d_out;
    float* atom = out;                 // 2,050,048 floats
    float* bond = out + ATOM_ELEMS;    // 157,810,688 floats

    // ws layout
    ushort* xb   = (ushort*)d_ws;                       // 2048*768 bf16  (3.15 MB)
    ushort* wcat = xb + (size_t)M_ROWS * DK;            // 1664*768 bf16  (2.56 MB)
    float*  p1   = (float*)(wcat + (size_t)N_PADR * DK);// 2048*301 f32   (2.47 MB)
    float*  p2   = p1 + P_ELEMS;                        // 2048*301 f32   (2.47 MB)

    // 1) pack to bf16 (+ zero-pad wcat rows 1603..1663)
    pack_bf16<<<dim3(2784), dim3(256), 0, stream>>>(x, Wa, Wb, xb, wcat);

    // 2) fused MFMA GEMM: atom + p1 + p2(+bb)
    gemm_mfma<<<dim3(N_PADR / BN, M_ROWS / BM), dim3(256), 0, stream>>>(
        xb, wcat, ba, bb, atom, p1, p2);

    // 3) bond broadcast
    bond_bcast<<<dim3(2048), dim3(320), 0, stream>>>(p1, p2, bond);
}

// Round 4
// 150.888 us; speedup vs baseline: 5.3323x; 2.3373x over previous
//
#include <hip/hip_runtime.h>

// ---------------- problem constants ----------------
#define DK      768
#define M_ROWS  2048          // 8*256
#define N_ATOM  1001
#define N_BOND  301
#define N_TOT   1603          // 1001 + 2*301
#define N_PADR  1664          // 26 * 64 (padded rows of Wcat)
#define ATOM_ELEMS 2050048    // 2048*1001
#define P_ELEMS    616448     // 2048*301
#define SLAB_F4    19264      // 256*301/4

typedef __attribute__((ext_vector_type(4))) float f32x4;
typedef __attribute__((ext_vector_type(8))) short bf16x8;

// exact RNE float->bf16
static __device__ __forceinline__ unsigned short f2bf(float f) {
    unsigned u = __float_as_uint(f);
    u += 0x7FFFu + ((u >> 16) & 1u);
    return (unsigned short)(u >> 16);
}

static __device__ __forceinline__ void gload_lds16(const void* g, void* l) {
    __builtin_amdgcn_global_load_lds(
        (const __attribute__((address_space(1))) unsigned*)g,
        (__attribute__((address_space(3))) unsigned*)l, 16, 0, 0);
}

// ---------------- pack: x, Wa, Wb(interleaved W1/W2) -> bf16 ----------------
__global__ __launch_bounds__(256) void pack_bf16(
    const float* __restrict__ x, const float* __restrict__ Wa,
    const float* __restrict__ Wb,
    ushort* __restrict__ xb, ushort* __restrict__ wcat)
{
    const int NX4 = (M_ROWS * DK) / 4;   // 393216
    const int NW4 = (N_PADR * DK) / 4;   // 319488
    int t = blockIdx.x * 256 + threadIdx.x;
    if (t < NX4) {
        float4 v = ((const float4*)x)[t];
        ushort4 o;
        o.x = f2bf(v.x); o.y = f2bf(v.y); o.z = f2bf(v.z); o.w = f2bf(v.w);
        ((ushort4*)xb)[t] = o;
    } else if (t < NX4 + NW4) {
        int u = t - NX4;
        int r = u / 192;                 // 192 float4 per row
        int c = (u - r * 192) * 4;
        float4 v = make_float4(0.f, 0.f, 0.f, 0.f);
        if (r < N_ATOM) {
            v = *(const float4*)(Wa + (size_t)r * DK + c);
        } else if (r < N_TOT) {
            int q = r - N_ATOM;
            v = *(const float4*)(Wb + (size_t)(q >> 1) * (2 * DK) + (q & 1) * DK + c);
        }
        ushort4 o;
        o.x = f2bf(v.x); o.y = f2bf(v.y); o.z = f2bf(v.z); o.w = f2bf(v.w);
        ((ushort4*)wcat)[u] = o;
    }
}

// ---------------- fused bf16 MFMA GEMM (global_load_lds + XOR swizzle) -------
// C[m,n] = sum_k xb[m,k] * wcat[n,k]; epilogue splits n into atom / p1 / p2(+bb)
// LDS layout: logical (row, chunk kc in [0,8)) of 16B stored at phys byte
//   row*128 + ((kc ^ (row&7)) << 4).  global_load_lds writes linearly:
//   wave segment s covers rows s*8..s*8+7; lane l -> row s*8+(l>>3),
//   phys chunk (l&7)  -> must fetch logical chunk (l&7)^(l>>3).
__global__ __launch_bounds__(256) void gemm_mfma(
    const ushort* __restrict__ xb, const ushort* __restrict__ wcat,
    const float* __restrict__ ba, const float* __restrict__ bb,
    float* __restrict__ atom, float* __restrict__ p1, float* __restrict__ p2)
{
    __shared__ char As[8192];   // 64 rows x 128B
    __shared__ char Bs[8192];

    const int tid  = threadIdx.x;
    const int lane = tid & 63;
    const int wid  = tid >> 6;     // 4 waves: 2x2
    const int wr   = wid >> 1;
    const int wc   = wid & 1;
    const int m0   = blockIdx.y * 64;
    const int n0   = blockIdx.x * 64;

    f32x4 acc[2][2] = {};

    const int lrow = lane >> 3;                 // 0..7
    const int lcx  = ((lane & 7) ^ lrow) * 8;   // inverse-swizzled k-chunk (elems)

    const ushort* Ag = xb   + (size_t)m0 * DK;
    const ushort* Bg = wcat + (size_t)n0 * DK;

    for (int k0 = 0; k0 < DK; k0 += 64) {
        __syncthreads();   // previous compute done before overwrite
        #pragma unroll
        for (int t = 0; t < 2; ++t) {
            const int s = wid + 4 * t;          // segment 0..7 (1KB each)
            gload_lds16(Ag + (size_t)(s * 8 + lrow) * DK + k0 + lcx, As + s * 1024);
            gload_lds16(Bg + (size_t)(s * 8 + lrow) * DK + k0 + lcx, Bs + s * 1024);
        }
        __syncthreads();   // compiler drains vmcnt(0) before s_barrier
        #pragma unroll
        for (int ks = 0; ks < 2; ++ks) {
            const int kc = ks * 4 + (lane >> 4);
            bf16x8 af[2], bfr[2];
            #pragma unroll
            for (int i = 0; i < 2; ++i) {
                int ra = wr * 32 + i * 16 + (lane & 15);
                af[i]  = *(const bf16x8*)(As + ra * 128 + ((kc ^ (ra & 7)) << 4));
                int rb = wc * 32 + i * 16 + (lane & 15);
                bfr[i] = *(const bf16x8*)(Bs + rb * 128 + ((kc ^ (rb & 7)) << 4));
            }
            #pragma unroll
            for (int i = 0; i < 2; ++i)
                #pragma unroll
                for (int j = 0; j < 2; ++j)
                    acc[i][j] = __builtin_amdgcn_mfma_f32_16x16x32_bf16(
                        af[i], bfr[j], acc[i][j], 0, 0, 0);
        }
    }

    // epilogue: D col = lane&15, row = (lane>>4)*4 + reg  [m89-verified, r2-passed]
    #pragma unroll
    for (int i = 0; i < 2; ++i) {
        #pragma unroll
        for (int j = 0; j < 2; ++j) {
            #pragma unroll
            for (int reg = 0; reg < 4; ++reg) {
                int m = m0 + wr * 32 + i * 16 + (lane >> 4) * 4 + reg;
                int n = n0 + wc * 32 + j * 16 + (lane & 15);
                float v = acc[i][j][reg];
                if (n < N_ATOM) {
                    atom[(size_t)m * N_ATOM + n] = v + ba[n];
                } else if (n < N_TOT) {
                    int q = n - N_ATOM, rr = q >> 1;
                    if (q & 1) p2[(size_t)m * N_BOND + rr] = v + bb[rr];
                    else       p1[(size_t)m * N_BOND + rr] = v;
                }
            }
        }
    }
}

// ---------------- bond broadcast, float4 flat form ----------------
// out slab(bi) flat f4 index f: elements e=4f..4f+3; out[e] = p2slab[e] + p1row[e%301]
// p2slab has identical flat layout -> p2 read is contiguous float4.
// n maintained incrementally: e += 1024 per iter -> n += 121 (mod 301).
__global__ __launch_bounds__(256) void bond_bcast(
    const float* __restrict__ p1, const float* __restrict__ p2,
    f32x4* __restrict__ out)
{
    __shared__ float p1s[344];          // index swizzle n + (n>>3), max 337
    const int bi  = blockIdx.x;         // 0..2047
    const int b   = bi >> 8;
    const int tid = threadIdx.x;

    for (int n = tid; n < N_BOND; n += 256)
        p1s[n + (n >> 3)] = p1[(size_t)bi * N_BOND + n];
    __syncthreads();

    const f32x4* p2f = (const f32x4*)(p2 + (size_t)(b << 8) * N_BOND);
    f32x4* of = out + (size_t)bi * SLAB_F4;

    int n = (4 * tid) % 301;
    for (int f = tid; f < SLAB_F4; f += 256) {
        f32x4 v = p2f[f];
        int n0 = n;
        int n1 = n + 1; if (n1 >= 301) n1 -= 301;
        int n2 = n + 2; if (n2 >= 301) n2 -= 301;
        int n3 = n + 3; if (n3 >= 301) n3 -= 301;
        v.x += p1s[n0 + (n0 >> 3)];
        v.y += p1s[n1 + (n1 >> 3)];
        v.z += p1s[n2 + (n2 >> 3)];
        v.w += p1s[n3 + (n3 >> 3)];
        __builtin_nontemporal_store(v, &of[f]);
        n += 121; if (n >= 301) n -= 301;
    }
}

// ---------------- launch ----------------
extern "C" void kernel_launch(void* const* d_in, const int* in_sizes, int n_in,
                              void* d_out, int out_size, void* d_ws, size_t ws_size,
                              hipStream_t stream) {
    const float* x  = (const float*)d_in[0];   // (8,256,768)
    const float* Wa = (const float*)d_in[1];   // (1001,768)
    const float* ba = (const float*)d_in[2];   // (1001,)
    const float* Wb = (const float*)d_in[3];   // (301,1536)
    const float* bb = (const float*)d_in[4];   // (301,)

    float* out  = (float*)d_out;
    float* atom = out;                 // 2,050,048 floats
    float* bond = out + ATOM_ELEMS;    // 157,810,688 floats

    // ws layout (16B-aligned sections)
    ushort* xb   = (ushort*)d_ws;                        // 2048*768 bf16
    ushort* wcat = xb + (size_t)M_ROWS * DK;             // 1664*768 bf16
    float*  p1   = (float*)(wcat + (size_t)N_PADR * DK); // 2048*301 f32
    float*  p2   = p1 + P_ELEMS;                         // 2048*301 f32

    pack_bf16<<<dim3(2784), dim3(256), 0, stream>>>(x, Wa, Wb, xb, wcat);

    gemm_mfma<<<dim3(N_PADR / 64, M_ROWS / 64), dim3(256), 0, stream>>>(
        xb, wcat, ba, bb, atom, p1, p2);

    bond_bcast<<<dim3(2048), dim3(256), 0, stream>>>(p1, p2, (f32x4*)bond);
}